// Round 6
// baseline (207.506 us; speedup 1.0000x reference)
//
#include <hip/hip_runtime.h>

#define N 256
#define C 128
#define H 4
#define D 32
#define NP (N*N)            // 65536 pairs
#define LN_EPS 1e-5f
#define LOG2E 1.4426950408889634f

using f32x4 = __attribute__((ext_vector_type(4))) float;
using bf8   = __attribute__((ext_vector_type(8))) short;   // 8 x bf16 (4 VGPRs)

__device__ __forceinline__ float bf2f(ushort u) {
    union { uint u; float f; } v; v.u = ((uint)u) << 16; return v.f;
}
__device__ __forceinline__ ushort f2bf(float f) {           // RNE
    union { float f; uint u; } v; v.f = f;
    uint u = v.u;
    u += 0x7fffu + ((u >> 16) & 1u);
    return (ushort)(u >> 16);
}
__device__ __forceinline__ ushort f2bf_trunc(float f) {     // truncate (1 VALU op)
    union { float f; uint u; } v; v.f = f;
    return (ushort)(v.u >> 16);
}

// ---------------------------------------------------------------- weights
// q-scale folds 1/sqrt(D) AND log2e (softmax uses exp2 directly)
__global__ __launch_bounds__(256) void prep_weights(
    const float* __restrict__ wq, const float* __restrict__ wk,
    const float* __restrict__ wv, const float* __restrict__ wg,
    const float* __restrict__ wo,
    ushort* __restrict__ Wcat, ushort* __restrict__ Wo)
{
    int t = blockIdx.x * 256 + threadIdx.x;    // 65536 threads
    const float scale = 0.17677669529663689f * LOG2E;
    float v;
    if (t < 16384)       v = wq[t] * scale;
    else if (t < 32768)  v = wk[t - 16384];
    else if (t < 49152)  v = wv[t - 32768];
    else                 v = wg[t - 49152];
    Wcat[t] = f2bf(v);
    if (t < 16384) Wo[t] = f2bf(wo[t]);
}

// ---------------------------------------------------------------- LN + triangle bias
// One wave per pair p=(q,k). fp32 LN in registers, 4 head-dots via wave
// reduction, writes ONLY tri_p (bf16*LOG2E, permuted to attn fragment layout:
//   qc=q>>4, quad=(q>>2)&3, r=q&3, n=k>>4, lrow=k&15; lane=quad*16+lrow;
//   v=n*4+r, j=v>>3, m=v&7; idx = h*65536 + ((qc*8+j)*64+lane)*8 + m ).
__global__ __launch_bounds__(256) void ln_tri_kernel(
    const float* __restrict__ x, const float* __restrict__ lnw,
    const float* __restrict__ lnb, const float* __restrict__ wb,
    ushort* __restrict__ tri_p)
{
    int wave = threadIdx.x >> 6, lane = threadIdx.x & 63;
    int p = blockIdx.x * 4 + wave;
    const float* xp = x + (size_t)p * C;
    float a0 = xp[lane], a1 = xp[lane + 64];
    float s = a0 + a1, ss = a0 * a0 + a1 * a1;
    #pragma unroll
    for (int m = 1; m < 64; m <<= 1) {
        s  += __shfl_xor(s, m, 64);
        ss += __shfl_xor(ss, m, 64);
    }
    float mean = s * (1.f / 128.f);
    float var  = ss * (1.f / 128.f) - mean * mean;
    float rstd = rsqrtf(var + LN_EPS);
    float v0 = (a0 - mean) * rstd * lnw[lane]      + lnb[lane];
    float v1 = (a1 - mean) * rstd * lnw[lane + 64] + lnb[lane + 64];

    float t[H];
    #pragma unroll
    for (int h = 0; h < H; h++)
        t[h] = v0 * wb[h * C + lane] + v1 * wb[h * C + 64 + lane];
    #pragma unroll
    for (int m = 1; m < 64; m <<= 1) {
        #pragma unroll
        for (int h = 0; h < H; h++) t[h] += __shfl_xor(t[h], m, 64);
    }
    if (lane == 0) {
        int q = p >> 8, k = p & 255;
        int qc = q >> 4, quad = (q >> 2) & 3, r = q & 3;
        int n = k >> 4, lrow = k & 15;
        int ln2 = quad * 16 + lrow;
        int v = n * 4 + r, j = v >> 3, m = v & 7;
        int base = ((qc * 8 + j) * 64 + ln2) * 8 + m;
        #pragma unroll
        for (int h = 0; h < H; h++)
            tri_p[h * 65536 + base] = f2bf(t[h] * LOG2E);
    }
}

// ---------------------------------------------------------------- fused row kernel
// grid 256 (one block per row i), 512 threads = 8 waves, 144 KB LDS.
// LN -> Xs; per head: QKV proj -> frag-ordered LDS, flash attention
// (wave-private P), gate MFMA (C/D layout == O layout), gated-O -> A-frags via
// LDS, out-proj accumulated in registers across heads; single fp32 out write.
__global__ __launch_bounds__(512, 2) void fused_row(
    const float* __restrict__ x, const float* __restrict__ lnw,
    const float* __restrict__ lnb, const ushort* __restrict__ Wcat,
    const float* __restrict__ bg, const ushort* __restrict__ Wo,
    const float* __restrict__ bo, const ushort* __restrict__ tri_p,
    const float* __restrict__ mask, float* __restrict__ out)
{
    __shared__ ushort Xs[128 * 256];   // 64 KB  xn row, swizzled 16B chunks
    __shared__ ushort Qf[8192];        // 16 KB  Q frags (pair-major chunks)
    __shared__ ushort Kf[8192];        // 16 KB  K frags
    __shared__ ushort Vf[8192];        // 16 KB  V^T frags (d-major, xor-swizzled)
    __shared__ ushort Pf[8][2048];     // 32 KB  per-wave P / gated-O frags

    int i    = blockIdx.x;
    int t    = threadIdx.x;
    int wave = t >> 6, lane = t & 63;
    int lrow = lane & 15, quad = lane >> 4;

    // ================= phase 0: LN of this row -> Xs =================
    {
        const float* xp = x + ((size_t)(i * N) + wave * 32) * C;
        float lw0 = lnw[lane], lw1 = lnw[lane + 64];
        float lb0 = lnb[lane], lb1 = lnb[lane + 64];
        #pragma unroll 4
        for (int jj = 0; jj < 32; jj++) {
            float a0 = xp[jj * C + lane], a1 = xp[jj * C + 64 + lane];
            float s = a0 + a1, ss = a0 * a0 + a1 * a1;
            #pragma unroll
            for (int m = 1; m < 64; m <<= 1) {
                s  += __shfl_xor(s, m, 64);
                ss += __shfl_xor(ss, m, 64);
            }
            float mean = s * (1.f / 128.f);
            float var  = ss * (1.f / 128.f) - mean * mean;
            float rstd = rsqrtf(var + LN_EPS);
            int p = wave * 32 + jj;
            int c80 = lane >> 3, c81 = 8 + (lane >> 3);
            Xs[(p * 16 + (c80 ^ (p & 7))) * 8 + (lane & 7)] =
                f2bf((a0 - mean) * rstd * lw0 + lb0);
            Xs[(p * 16 + (c81 ^ (p & 7))) * 8 + (lane & 7)] =
                f2bf((a1 - mean) * rstd * lw1 + lb1);
        }
    }
    // mask bias per lane's 16 key-columns (log2e-folded)
    float mb[16];
    #pragma unroll
    for (int n = 0; n < 16; n++)
        mb[n] = (1e9f * LOG2E) * (mask[i * N + n * 16 + lrow] - 1.0f);
    __syncthreads();

    // xn fragments for this wave's two pair-tiles (reused for Q/K B, V A, gate A)
    bf8 xf[2][4];
    #pragma unroll
    for (int tt = 0; tt < 2; tt++)
        #pragma unroll
        for (int ks = 0; ks < 4; ks++) {
            int pr = (wave * 2 + tt) * 16 + lrow;
            xf[tt][ks] = *(const bf8*)&Xs[(pr * 16 + ((ks * 4 + quad) ^ (pr & 7))) * 8];
        }

    f32x4 outacc[2][8];
    #pragma unroll
    for (int cc = 0; cc < 2; cc++)
        #pragma unroll
        for (int n8 = 0; n8 < 8; n8++) outacc[cc][n8] = (f32x4){0.f, 0.f, 0.f, 0.f};

    ushort* Pw = &Pf[wave][0];
    int pq = quad * 32 + (lrow & 7);
    int l3 = (lrow >> 3) & 1;

    #pragma unroll 1
    for (int h = 0; h < H; h++) {
        const ushort* trih = tri_p + (size_t)h * 65536;
        // ---- QKV projection into frag-ordered LDS ----
        {
            const ushort* WqB = Wcat + (size_t)(h * D) * C;
            const ushort* WkB = Wcat + (size_t)(128 + h * D) * C;
            bf8 aQ[2][4], aK[2][4];
            #pragma unroll
            for (int mm = 0; mm < 2; mm++)
                #pragma unroll
                for (int ks = 0; ks < 4; ks++) {
                    aQ[mm][ks] = *(const bf8*)(WqB + (size_t)(mm * 16 + lrow) * C + ks * 32 + quad * 8);
                    aK[mm][ks] = *(const bf8*)(WkB + (size_t)(mm * 16 + lrow) * C + ks * 32 + quad * 8);
                }
            #pragma unroll
            for (int tt = 0; tt < 2; tt++) {
                int n = wave * 2 + tt;
                f32x4 accQ[2], accK[2];
                #pragma unroll
                for (int mm = 0; mm < 2; mm++) {
                    accQ[mm] = (f32x4){0.f, 0.f, 0.f, 0.f};
                    accK[mm] = (f32x4){0.f, 0.f, 0.f, 0.f};
                }
                #pragma unroll
                for (int ks = 0; ks < 4; ks++)
                    #pragma unroll
                    for (int mm = 0; mm < 2; mm++) {
                        accQ[mm] = __builtin_amdgcn_mfma_f32_16x16x32_bf16(aQ[mm][ks], xf[tt][ks], accQ[mm], 0, 0, 0);
                        accK[mm] = __builtin_amdgcn_mfma_f32_16x16x32_bf16(aK[mm][ks], xf[tt][ks], accK[mm], 0, 0, 0);
                    }
                // value (pair = n*16+lrow? no: pair = n*16 + col, col=lane&15=lrow), d = mm*16+quad*4+r
                #pragma unroll
                for (int mm = 0; mm < 2; mm++) {
                    int addr = n * 512 + (mm * 2 + (quad >> 1)) * 128 + lrow * 8 + (quad & 1) * 4;
                    ushort4 pk;
                    pk.x = f2bf(accQ[mm][0]); pk.y = f2bf(accQ[mm][1]);
                    pk.z = f2bf(accQ[mm][2]); pk.w = f2bf(accQ[mm][3]);
                    *(ushort4*)&Qf[addr] = pk;
                    pk.x = f2bf(accK[mm][0]); pk.y = f2bf(accK[mm][1]);
                    pk.z = f2bf(accK[mm][2]); pk.w = f2bf(accK[mm][3]);
                    *(ushort4*)&Kf[addr] = pk;
                }
            }
            // V: A = xn (pairs), B = Wv (d)  -> lanes hold key-consecutive values
            const ushort* WvB = Wcat + (size_t)(256 + h * D) * C;
            bf8 bV[2][4];
            #pragma unroll
            for (int nn = 0; nn < 2; nn++)
                #pragma unroll
                for (int ks = 0; ks < 4; ks++)
                    bV[nn][ks] = *(const bf8*)(WvB + (size_t)(nn * 16 + lrow) * C + ks * 32 + quad * 8);
            #pragma unroll
            for (int tt = 0; tt < 2; tt++) {
                int m = wave * 2 + tt;
                f32x4 accV[2];
                accV[0] = (f32x4){0.f, 0.f, 0.f, 0.f};
                accV[1] = (f32x4){0.f, 0.f, 0.f, 0.f};
                #pragma unroll
                for (int ks = 0; ks < 4; ks++)
                    #pragma unroll
                    for (int nn = 0; nn < 2; nn++)
                        accV[nn] = __builtin_amdgcn_mfma_f32_16x16x32_bf16(xf[tt][ks], bV[nn][ks], accV[nn], 0, 0, 0);
                // value (key = m*16+quad*4+r, d = nn*16+lrow)
                #pragma unroll
                for (int nn = 0; nn < 2; nn++) {
                    int d = nn * 16 + lrow;
                    int addr = (d * 32 + ((m * 2 + (quad >> 1)) ^ (lrow & 7))) * 8 + (quad & 1) * 4;
                    ushort4 pk;
                    pk.x = f2bf(accV[nn][0]); pk.y = f2bf(accV[nn][1]);
                    pk.z = f2bf(accV[nn][2]); pk.w = f2bf(accV[nn][3]);
                    *(ushort4*)&Vf[addr] = pk;
                }
            }
        }
        __syncthreads();

        // ---- attention: both q-chunks of this wave ----
        f32x4 o[2][2];
        float inv[2][4];
        #pragma unroll
        for (int cc = 0; cc < 2; cc++) {
            int qc = wave * 2 + cc;
            bf8 aq = *(const bf8*)&Qf[qc * 512 + quad * 128 + lrow * 8];
            float sum[4] = {0.f, 0.f, 0.f, 0.f};
            o[cc][0] = (f32x4){0.f, 0.f, 0.f, 0.f};
            o[cc][1] = (f32x4){0.f, 0.f, 0.f, 0.f};

            #pragma unroll
            for (int hf = 0; hf < 2; hf++) {
                f32x4 s8[8];
                #pragma unroll
                for (int n8 = 0; n8 < 8; n8++) {
                    bf8 kf = *(const bf8*)&Kf[(hf * 8 + n8) * 512 + quad * 128 + lrow * 8];
                    s8[n8] = __builtin_amdgcn_mfma_f32_16x16x32_bf16(
                        aq, kf, (f32x4){0.f, 0.f, 0.f, 0.f}, 0, 0, 0);
                }
                const ushort* tp = trih + ((size_t)(qc * 8 + hf * 4) * 64 + lane) * 8;
                bf8 tf[4];
                #pragma unroll
                for (int jj = 0; jj < 4; jj++)
                    tf[jj] = *(const bf8*)(tp + jj * 512);

                #pragma unroll
                for (int n8 = 0; n8 < 8; n8++) {
                    int pa = (n8 >> 1) * 512 + (((n8 << 1) + l3) & 3) * 128 + pq;
                    #pragma unroll
                    for (int r = 0; r < 4; r++) {
                        float tb = bf2f(((const ushort*)&tf[n8 >> 1])[((n8 & 1) << 2) + r]);
                        float e  = exp2f(s8[n8][r] + tb + mb[hf * 8 + n8]);
                        sum[r]  += e;
                        Pw[pa + r * 8] = f2bf_trunc(e);
                    }
                }
                __asm__ volatile("s_waitcnt lgkmcnt(0)" ::: "memory");

                #pragma unroll
                for (int ks = 0; ks < 4; ks++) {
                    bf8 ap = *(const bf8*)&Pw[(ks * 64 + lane) * 8];
                    int ksg = hf * 4 + ks;
                    #pragma unroll
                    for (int nv = 0; nv < 2; nv++) {
                        bf8 bv = *(const bf8*)&Vf[((nv * 16 + lrow) * 32 + ((ksg * 4 + quad) ^ (lrow & 7))) * 8];
                        o[cc][nv] = __builtin_amdgcn_mfma_f32_16x16x32_bf16(ap, bv, o[cc][nv], 0, 0, 0);
                    }
                }
            }
            #pragma unroll
            for (int r = 0; r < 4; r++) {
                float s = sum[r];
                s += __shfl_xor(s, 1, 64);
                s += __shfl_xor(s, 2, 64);
                s += __shfl_xor(s, 4, 64);
                s += __shfl_xor(s, 8, 64);
                inv[cc][r] = 1.f / s;
            }
        }

        // ---- gate (C/D layout matches O), gated-O -> A-frags in Pw ----
        {
            const ushort* WgB = Wcat + (size_t)(384 + h * D) * C;
            bf8 gW[2][4];
            float bgv[2];
            #pragma unroll
            for (int nn = 0; nn < 2; nn++) {
                bgv[nn] = bg[h * D + nn * 16 + lrow];
                #pragma unroll
                for (int ks = 0; ks < 4; ks++)
                    gW[nn][ks] = *(const bf8*)(WgB + (size_t)(nn * 16 + lrow) * C + ks * 32 + quad * 8);
            }
            #pragma unroll
            for (int cc = 0; cc < 2; cc++) {
                f32x4 gacc[2];
                gacc[0] = (f32x4){0.f, 0.f, 0.f, 0.f};
                gacc[1] = (f32x4){0.f, 0.f, 0.f, 0.f};
                #pragma unroll
                for (int ks = 0; ks < 4; ks++)
                    #pragma unroll
                    for (int nn = 0; nn < 2; nn++)
                        gacc[nn] = __builtin_amdgcn_mfma_f32_16x16x32_bf16(xf[cc][ks], gW[nn][ks], gacc[nn], 0, 0, 0);
                #pragma unroll
                for (int nv = 0; nv < 2; nv++) {
                    #pragma unroll
                    for (int r = 0; r < 4; r++) {
                        float g  = 1.f / (1.f + __expf(-(gacc[nv][r] + bgv[nv])));
                        float og = o[cc][nv][r] * inv[cc][r] * g;
                        // (q&15 = quad*4+r, d31 = nv*16+lrow)
                        Pw[cc * 512 + (nv * 2 + (lrow >> 3)) * 128 + (quad * 4 + r) * 8 + (lrow & 7)]
                            = f2bf(og);
                    }
                }
            }
            __asm__ volatile("s_waitcnt lgkmcnt(0)" ::: "memory");

            // ---- out-proj partial: kstep = this head ----
            bf8 woB[8];
            #pragma unroll
            for (int n8 = 0; n8 < 8; n8++)
                woB[n8] = *(const bf8*)(Wo + (size_t)(n8 * 16 + lrow) * 128 + h * D + quad * 8);
            #pragma unroll
            for (int cc = 0; cc < 2; cc++) {
                bf8 ag = *(const bf8*)&Pw[cc * 512 + quad * 128 + lrow * 8];
                #pragma unroll
                for (int n8 = 0; n8 < 8; n8++)
                    outacc[cc][n8] = __builtin_amdgcn_mfma_f32_16x16x32_bf16(ag, woB[n8], outacc[cc][n8], 0, 0, 0);
            }
        }
        __syncthreads();   // protect Qf/Kf/Vf before next head
    }

    // ================= epilogue: out = outacc + bo =================
    #pragma unroll
    for (int cc = 0; cc < 2; cc++) {
        #pragma unroll
        for (int n8 = 0; n8 < 8; n8++) {
            int col = n8 * 16 + lrow;
            float bias = bo[col];
            #pragma unroll
            for (int r = 0; r < 4; r++) {
                int q = (wave * 2 + cc) * 16 + quad * 4 + r;
                out[((size_t)(i * N + q)) * C + col] = outacc[cc][n8][r] + bias;
            }
        }
    }
}

// ---------------------------------------------------------------- launch
extern "C" void kernel_launch(void* const* d_in, const int* in_sizes, int n_in,
                              void* d_out, int out_size, void* d_ws, size_t ws_size,
                              hipStream_t stream)
{
    const float* x    = (const float*)d_in[0];
    const float* mask = (const float*)d_in[1];
    const float* lnw  = (const float*)d_in[2];
    const float* lnb  = (const float*)d_in[3];
    const float* wb   = (const float*)d_in[4];
    const float* wq   = (const float*)d_in[5];
    const float* wk   = (const float*)d_in[6];
    const float* wv   = (const float*)d_in[7];
    const float* wg   = (const float*)d_in[8];
    const float* bg   = (const float*)d_in[9];
    const float* wo   = (const float*)d_in[10];
    const float* bo   = (const float*)d_in[11];
    float* out = (float*)d_out;

    uintptr_t w = (uintptr_t)d_ws;
    ushort* tri_p = (ushort*)w; w += (size_t)H * NP * 2;   // 0.5 MB
    ushort* Wcat  = (ushort*)w; w += 512 * 128 * 2;        // 128 KB
    ushort* Wo    = (ushort*)w; w += 128 * 128 * 2;        // 32 KB

    prep_weights<<<256, 256, 0, stream>>>(wq, wk, wv, wg, wo, Wcat, Wo);
    ln_tri_kernel<<<NP / 4, 256, 0, stream>>>(x, lnw, lnb, wb, tri_p);
    fused_row<<<N, 512, 0, stream>>>(x, lnw, lnb, Wcat, bg, Wo, bo, tri_p, mask, out);
}